// Round 9
// baseline (176.693 us; speedup 1.0000x reference)
//
#include <hip/hip_runtime.h>
#include <hip/hip_bf16.h>

#define DD 32
#define P_MAX 118
#define N_MAX 236
#define TBL (P_MAX * N_MAX)

// native clang vector types for nontemporal builtins (HIP_vector_type invalid)
typedef int   ivec4 __attribute__((ext_vector_type(4)));
typedef float fvec4 __attribute__((ext_vector_type(4)));

// ws float offsets
#define PST 0                       // proton states  118*32
#define NST (P_MAX * DD)            // neutron states 236*32 at 3776
#define UOF ((P_MAX + N_MAX) * DD)  // U_T 32x118 at 11328
#define VOF (UOF + DD * P_MAX)      // V_T 32x236 at 15104
#define TOF (VOF + DD * N_MAX)      // table (float2) at 22656 floats

// ---------------------------------------------------------------------------
// Kernel A: chain (RAW ASM inner loop) + own-side UV, partitioned by side.
// 2 blocks x 256. Block s: wave 0 runs side-s chain; __syncthreads(); all 4
// waves compute side-s uv tasks.
// R8 finding: VGPR_Count=36 (=32 w + 4 temps) both with and without the pin,
// dur unchanged 70us -> weights likely resident; the 712 cyc/step is the
// compiler's SCHEDULE (readlane->SGPR->fmac hazards + exp/rcp serialization).
// Fix: hand-written schedule. Weights pinned v40..v71 (8x dwordx4, loaded
// once), silu = mul(-log2e)/exp/add/rcp/mul, 32 readlane/fmac pairs
// pipelined distance-4 through s20..s23, 4 accumulators, 1 store/step.
// ---------------------------------------------------------------------------
__global__ __launch_bounds__(256, 1) void chain_uv_kernel(
    const float* __restrict__ emb,
    const float* __restrict__ Wp, const float* __restrict__ bp,
    const float* __restrict__ Wn, const float* __restrict__ bn,
    const float* __restrict__ W1, const float* __restrict__ b1,
    float* __restrict__ ws)
{
    const int side = blockIdx.x;          // 0 = proton, 1 = neutron
    const int wid  = threadIdx.x >> 6;
    const int lane = threadIdx.x & 63;

    // ---- phase 1: chain on wave 0, raw asm ----
    if (wid == 0) {
        const int ch = lane & 31;
        const float* W  = side ? Wn : Wp;
        const float* bb = side ? bn : bp;
        const float* wrow = W + ch * 32;
        const float bias = bb[ch];
        const float p0 = emb[side * DD + ch];
        float* outp = ws + (side ? NST : PST);
        const int voff0 = ch * 4;
        const int len = side ? N_MAX : P_MAX;

        asm volatile(
            "global_load_dwordx4 v[40:43], %[wr], off\n\t"
            "global_load_dwordx4 v[44:47], %[wr], off offset:16\n\t"
            "global_load_dwordx4 v[48:51], %[wr], off offset:32\n\t"
            "global_load_dwordx4 v[52:55], %[wr], off offset:48\n\t"
            "global_load_dwordx4 v[56:59], %[wr], off offset:64\n\t"
            "global_load_dwordx4 v[60:63], %[wr], off offset:80\n\t"
            "global_load_dwordx4 v[64:67], %[wr], off offset:96\n\t"
            "global_load_dwordx4 v[68:71], %[wr], off offset:112\n\t"
            "v_mov_b32 v72, %[p0]\n\t"
            "v_mov_b32 v78, %[bias]\n\t"
            "v_mov_b32 v79, %[voff]\n\t"
            "s_mov_b32 s30, %[len]\n\t"
            "s_waitcnt vmcnt(0)\n\t"
            "Lchain_%=:\n\t"
            // s = p * rcp(1 + exp2(p * -log2(e)))
            "v_mul_f32 v77, 0xbfb8aa3b, v72\n\t"
            "v_exp_f32 v77, v77\n\t"
            "s_nop 1\n\t"
            "v_add_f32 v77, 1.0, v77\n\t"
            "v_rcp_f32 v77, v77\n\t"
            "s_nop 1\n\t"
            "v_mul_f32 v77, v72, v77\n\t"
            // accs: a0=bias, a1..a3=0
            "v_mov_b32 v73, v78\n\t"
            "v_mov_b32 v74, 0\n\t"
            "v_mov_b32 v75, 0\n\t"
            "v_mov_b32 v76, 0\n\t"
            // prime 4 broadcast slots
            "v_readlane_b32 s20, v77, 0\n\t"
            "v_readlane_b32 s21, v77, 1\n\t"
            "v_readlane_b32 s22, v77, 2\n\t"
            "v_readlane_b32 s23, v77, 3\n\t"
            // k=0..27: fmac k ; readlane k+4 (distance-4 pipeline)
            "v_fmac_f32 v73, s20, v40\n\t"
            "v_readlane_b32 s20, v77, 4\n\t"
            "v_fmac_f32 v74, s21, v41\n\t"
            "v_readlane_b32 s21, v77, 5\n\t"
            "v_fmac_f32 v75, s22, v42\n\t"
            "v_readlane_b32 s22, v77, 6\n\t"
            "v_fmac_f32 v76, s23, v43\n\t"
            "v_readlane_b32 s23, v77, 7\n\t"
            "v_fmac_f32 v73, s20, v44\n\t"
            "v_readlane_b32 s20, v77, 8\n\t"
            "v_fmac_f32 v74, s21, v45\n\t"
            "v_readlane_b32 s21, v77, 9\n\t"
            "v_fmac_f32 v75, s22, v46\n\t"
            "v_readlane_b32 s22, v77, 10\n\t"
            "v_fmac_f32 v76, s23, v47\n\t"
            "v_readlane_b32 s23, v77, 11\n\t"
            "v_fmac_f32 v73, s20, v48\n\t"
            "v_readlane_b32 s20, v77, 12\n\t"
            "v_fmac_f32 v74, s21, v49\n\t"
            "v_readlane_b32 s21, v77, 13\n\t"
            "v_fmac_f32 v75, s22, v50\n\t"
            "v_readlane_b32 s22, v77, 14\n\t"
            "v_fmac_f32 v76, s23, v51\n\t"
            "v_readlane_b32 s23, v77, 15\n\t"
            "v_fmac_f32 v73, s20, v52\n\t"
            "v_readlane_b32 s20, v77, 16\n\t"
            "v_fmac_f32 v74, s21, v53\n\t"
            "v_readlane_b32 s21, v77, 17\n\t"
            "v_fmac_f32 v75, s22, v54\n\t"
            "v_readlane_b32 s22, v77, 18\n\t"
            "v_fmac_f32 v76, s23, v55\n\t"
            "v_readlane_b32 s23, v77, 19\n\t"
            "v_fmac_f32 v73, s20, v56\n\t"
            "v_readlane_b32 s20, v77, 20\n\t"
            "v_fmac_f32 v74, s21, v57\n\t"
            "v_readlane_b32 s21, v77, 21\n\t"
            "v_fmac_f32 v75, s22, v58\n\t"
            "v_readlane_b32 s22, v77, 22\n\t"
            "v_fmac_f32 v76, s23, v59\n\t"
            "v_readlane_b32 s23, v77, 23\n\t"
            "v_fmac_f32 v73, s20, v60\n\t"
            "v_readlane_b32 s20, v77, 24\n\t"
            "v_fmac_f32 v74, s21, v61\n\t"
            "v_readlane_b32 s21, v77, 25\n\t"
            "v_fmac_f32 v75, s22, v62\n\t"
            "v_readlane_b32 s22, v77, 26\n\t"
            "v_fmac_f32 v76, s23, v63\n\t"
            "v_readlane_b32 s23, v77, 27\n\t"
            "v_fmac_f32 v73, s20, v64\n\t"
            "v_readlane_b32 s20, v77, 28\n\t"
            "v_fmac_f32 v74, s21, v65\n\t"
            "v_readlane_b32 s21, v77, 29\n\t"
            "v_fmac_f32 v75, s22, v66\n\t"
            "v_readlane_b32 s22, v77, 30\n\t"
            "v_fmac_f32 v76, s23, v67\n\t"
            "v_readlane_b32 s23, v77, 31\n\t"
            // tail k=28..31
            "v_fmac_f32 v73, s20, v68\n\t"
            "v_fmac_f32 v74, s21, v69\n\t"
            "v_fmac_f32 v75, s22, v70\n\t"
            "v_fmac_f32 v76, s23, v71\n\t"
            // p = (a0+a1)+(a2+a3)
            "v_add_f32 v73, v73, v74\n\t"
            "v_add_f32 v75, v75, v76\n\t"
            "v_add_f32 v72, v73, v75\n\t"
            // store state (lanes 32-63 duplicate same addr/value: harmless)
            "global_store_dword v79, v72, %[ob]\n\t"
            "v_add_u32 v79, 128, v79\n\t"
            "s_sub_i32 s30, s30, 1\n\t"
            "s_cmp_lg_u32 s30, 0\n\t"
            "s_cbranch_scc1 Lchain_%=\n\t"
            "s_waitcnt vmcnt(0)\n\t"
            :
            : [wr]"v"(wrow), [p0]"v"(p0), [bias]"v"(bias),
              [voff]"v"(voff0), [len]"s"(len), [ob]"s"(outp)
            : "v40","v41","v42","v43","v44","v45","v46","v47",
              "v48","v49","v50","v51","v52","v53","v54","v55",
              "v56","v57","v58","v59","v60","v61","v62","v63",
              "v64","v65","v66","v67","v68","v69","v70","v71",
              "v72","v73","v74","v75","v76","v77","v78","v79",
              "s20","s21","s22","s23","s30","scc","memory");
    }

    __syncthreads();

    // ---- phase 2: own-side uv (control, unchanged) ----
    // proton: 64 tasks (j in [0,32), bx in {0,1}), 16 per wave
    // neutron: 128 tasks (j in [0,32), bx in {0..3}), 32 per wave
    const int tasks_per_wave = side ? 32 : 16;
    const int base = side ? NST : PST;
    const int len2 = side ? N_MAX : P_MAX;
    for (int i = 0; i < tasks_per_wave; ++i) {
        const int tau = wid * tasks_per_wave + i;
        int j, bx;
        if (side) { j = tau >> 2; bx = tau & 3; }
        else      { j = tau >> 1; bx = tau & 1; }
        const int t = bx * 64 + lane;
        if (t >= len2) continue;

        const float* st = ws + base + t * DD;
        const float* wr1 = W1 + j * 64 + (side ? 32 : 0);
        float acc = side ? b1[j] : 0.0f;
#pragma unroll
        for (int q = 0; q < 8; ++q) {
            float4 s4 = reinterpret_cast<const float4*>(st)[q];
            acc = fmaf(s4.x, wr1[4 * q + 0], acc);
            acc = fmaf(s4.y, wr1[4 * q + 1], acc);
            acc = fmaf(s4.z, wr1[4 * q + 2], acc);
            acc = fmaf(s4.w, wr1[4 * q + 3], acc);
        }
        if (side) ws[VOF + j * N_MAX + t] = acc;
        else      ws[UOF + j * P_MAX + t] = acc;
    }
}

// ---------------------------------------------------------------------------
// Kernel B (control): build the table. Per thread:
//   h = silu(U_T[:,pi] + V_T[:,ni]); layernorm; W2 matvec; Wr readout.
// ---------------------------------------------------------------------------
__global__ __launch_bounds__(64, 1) void table_kernel(
    const float* __restrict__ ws,
    const float* __restrict__ ln_g, const float* __restrict__ ln_b,
    const float* __restrict__ W2, const float* __restrict__ b2,
    const float* __restrict__ Wr, const float* __restrict__ br,
    float2* __restrict__ table)
{
    const int e = blockIdx.x * 64 + threadIdx.x;
    if (e >= TBL) return;
    const int pi = e / N_MAX;
    const int ni = e - pi * N_MAX;

    const float* UT = ws + UOF;   // 32 x 118
    const float* VT = ws + VOF;   // 32 x 236

    float h[32];
    float mu = 0.0f;
#pragma unroll
    for (int j = 0; j < 32; ++j) {
        float a = UT[j * P_MAX + pi] + VT[j * N_MAX + ni];
        float ee = __expf(-a);
        float s = a * __builtin_amdgcn_rcpf(1.0f + ee);
        h[j] = s;
        mu += s;
    }
    mu *= (1.0f / 32.0f);
    float var = 0.0f;
#pragma unroll
    for (int j = 0; j < 32; ++j) {
        float d = h[j] - mu;
        var = fmaf(d, d, var);
    }
    var *= (1.0f / 32.0f);
    const float inv = __builtin_amdgcn_rsqf(var + 1e-5f);
#pragma unroll
    for (int j = 0; j < 32; ++j)
        h[j] = (h[j] - mu) * inv * ln_g[j] + ln_b[j];

    // h2 = h @ W2^T + b2
    float h2[32];
#pragma unroll
    for (int j0 = 0; j0 < 32; j0 += 8) {
        float acc[8];
#pragma unroll
        for (int u = 0; u < 8; ++u) acc[u] = b2[j0 + u];
#pragma unroll
        for (int k = 0; k < 32; ++k) {
#pragma unroll
            for (int u = 0; u < 8; ++u)
                acc[u] = fmaf(h[k], W2[(j0 + u) * 32 + k], acc[u]);
        }
#pragma unroll
        for (int u = 0; u < 8; ++u) h2[j0 + u] = acc[u];
    }

    float o0 = br[0], o1 = br[1];
    float p0 = 0.0f, p1 = 0.0f;
#pragma unroll
    for (int k = 0; k < 32; k += 2) {
        o0 = fmaf(h2[k], Wr[k], o0);
        p0 = fmaf(h2[k + 1], Wr[k + 1], p0);
        o1 = fmaf(h2[k], Wr[32 + k], o1);
        p1 = fmaf(h2[k + 1], Wr[32 + k + 1], p1);
    }
    table[e] = make_float2(o0 + p0, o1 + p1);
}

// ---------------------------------------------------------------------------
// Kernel C (control): gather, 4 samples/thread. Nontemporal on the x/out
// streams (read/write-once, 8 MB each) so L2 stays dedicated to the table.
// ---------------------------------------------------------------------------
__global__ __launch_bounds__(256) void gather_kernel(
    const ivec4* __restrict__ x4,
    const float2* __restrict__ table,
    fvec4* __restrict__ out4,
    int B4)
{
    const int i = blockIdx.x * 256 + threadIdx.x;
    if (i >= B4) return;
    ivec4 a = __builtin_nontemporal_load(x4 + 2 * i);
    ivec4 b = __builtin_nontemporal_load(x4 + 2 * i + 1);
    float2 t0 = table[(a.x - 1) * N_MAX + (a.y - 1)];
    float2 t1 = table[(a.z - 1) * N_MAX + (a.w - 1)];
    float2 t2 = table[(b.x - 1) * N_MAX + (b.y - 1)];
    float2 t3 = table[(b.z - 1) * N_MAX + (b.w - 1)];
    fvec4 o0v = {t0.x, t0.y, t1.x, t1.y};
    fvec4 o1v = {t2.x, t2.y, t3.x, t3.y};
    __builtin_nontemporal_store(o0v, out4 + 2 * i);
    __builtin_nontemporal_store(o1v, out4 + 2 * i + 1);
}

extern "C" void kernel_launch(void* const* d_in, const int* in_sizes, int n_in,
                              void* d_out, int out_size, void* d_ws, size_t ws_size,
                              hipStream_t stream) {
    const int*   x    = (const int*)d_in[0];
    const float* emb  = (const float*)d_in[1];
    const float* Wp   = (const float*)d_in[2];
    const float* bp   = (const float*)d_in[3];
    const float* Wn   = (const float*)d_in[4];
    const float* bn   = (const float*)d_in[5];
    const float* W1   = (const float*)d_in[6];
    const float* b1   = (const float*)d_in[7];
    const float* ln_g = (const float*)d_in[8];
    const float* ln_b = (const float*)d_in[9];
    const float* W2   = (const float*)d_in[10];
    const float* b2   = (const float*)d_in[11];
    const float* Wr   = (const float*)d_in[12];
    const float* br   = (const float*)d_in[13];

    const int B = in_sizes[0] / 2;

    float* wsf = (float*)d_ws;
    float2* table = (float2*)(wsf + TOF);

    chain_uv_kernel<<<2, 256, 0, stream>>>(emb, Wp, bp, Wn, bn, W1, b1, wsf);

    table_kernel<<<(TBL + 63) / 64, 64, 0, stream>>>(
        wsf, ln_g, ln_b, W2, b2, Wr, br, table);

    gather_kernel<<<(B / 4 + 255) / 256, 256, 0, stream>>>(
        (const ivec4*)x, table, (fvec4*)d_out, B / 4);
}